// Round 1
// baseline (653.515 us; speedup 1.0000x reference)
//
#include <hip/hip_runtime.h>
#include <hip/hip_bf16.h>

// Problem constants
constexpr int Bn  = 128;   // batch
constexpr int Ln  = 200;   // sentences
constexpr int D2n = 1024;  // 2*SH
constexpr int G3n = 1536;  // 3*EH
constexpr int Tn  = 3;
constexpr int Nn  = 512;   // A (attention dim) == d_proj cols
constexpr int Kn  = 1024;  // d_proj K

typedef unsigned short ushort;
typedef float f32x4 __attribute__((ext_vector_type(4)));
typedef __bf16 bf16x8 __attribute__((ext_vector_type(8)));
typedef ushort ushort8v __attribute__((ext_vector_type(8)));

__device__ __forceinline__ ushort f2bf(float f) {   // RNE float->bf16
  unsigned u = __float_as_uint(f);
  unsigned r = (u + 0x7fffu + ((u >> 16) & 1u)) >> 16;
  return (ushort)r;
}
__device__ __forceinline__ float bf2f(ushort h) {
  return __uint_as_float(((unsigned)h) << 16);
}

__device__ __forceinline__ void gld_lds16(const ushort* g, ushort* l) {
  __builtin_amdgcn_global_load_lds(
      (const __attribute__((address_space(1))) unsigned int*)g,
      (__attribute__((address_space(3))) unsigned int*)l, 16, 0, 0);
}

__device__ __forceinline__ void cvt8(const float4 a, const float4 b,
                                     ushort8v& h, ushort8v& l) {
  float f[8] = {a.x, a.y, a.z, a.w, b.x, b.y, b.z, b.w};
  #pragma unroll
  for (int i = 0; i < 8; ++i) {
    ushort hi = f2bf(f[i]);
    h[i] = hi;
    l[i] = f2bf(f[i] - bf2f(hi));
  }
}

// ---------------------------------------------------------------------------
// gather last_back = sent[:, 0, 512:1024]
__global__ void k_gather_lastb(const float* __restrict__ sent, float* __restrict__ lastb) {
  int i = blockIdx.x * 256 + threadIdx.x;        // 65536 = 128*512
  int b = i >> 9, k = i & 511;
  lastb[i] = sent[(size_t)b * (Ln * D2n) + 512 + k];
}

// ---------------------------------------------------------------------------
// split W (fp32, N elements) into hi/lo bf16
__global__ void k_splitW(const float* __restrict__ W, ushort* __restrict__ hi,
                         ushort* __restrict__ lo) {
  int i = blockIdx.x * 256 + threadIdx.x;        // element/4
  float4 v = ((const float4*)W)[i];
  ushort4 h, l;
  h.x = f2bf(v.x); l.x = f2bf(v.x - bf2f(h.x));
  h.y = f2bf(v.y); l.y = f2bf(v.y - bf2f(h.y));
  h.z = f2bf(v.z); l.z = f2bf(v.z - bf2f(h.z));
  h.w = f2bf(v.w); l.w = f2bf(v.w - bf2f(h.w));
  ((ushort4*)hi)[i] = h;
  ((ushort4*)lo)[i] = l;
}

// ---------------------------------------------------------------------------
// small GEMM: out[b,j] = act(bias[j] + sum_k in[b,k] * W[j,k])
template<int K, int ACT>
__launch_bounds__(256)
__global__ void k_small_gemm(const float* __restrict__ in, const float* __restrict__ W,
                             const float* __restrict__ bias, float* __restrict__ out, int J) {
  __shared__ float s[16 * K];
  const int b0 = blockIdx.y * 16;
  const int jl = threadIdx.x & 63;
  const int j  = blockIdx.x * 64 + jl;
  const int bg = (threadIdx.x >> 6) * 4;         // 0,4,8,12

  const float4* inp4 = (const float4*)(in + (size_t)b0 * K);
  float4* s4 = (float4*)s;
  for (int i = threadIdx.x; i < 4 * K; i += 256) s4[i] = inp4[i];
  __syncthreads();

  const float4* w4 = (const float4*)(W + (size_t)j * K);
  const float4* r0 = (const float4*)(s + (size_t)(bg + 0) * K);
  const float4* r1 = (const float4*)(s + (size_t)(bg + 1) * K);
  const float4* r2 = (const float4*)(s + (size_t)(bg + 2) * K);
  const float4* r3 = (const float4*)(s + (size_t)(bg + 3) * K);

  float acc0 = 0.f, acc1 = 0.f, acc2 = 0.f, acc3 = 0.f;
  #pragma unroll 4
  for (int k4 = 0; k4 < K / 4; ++k4) {
    float4 wv = w4[k4];
    float4 a;
    a = r0[k4]; acc0 += wv.x*a.x + wv.y*a.y + wv.z*a.z + wv.w*a.w;
    a = r1[k4]; acc1 += wv.x*a.x + wv.y*a.y + wv.z*a.z + wv.w*a.w;
    a = r2[k4]; acc2 += wv.x*a.x + wv.y*a.y + wv.z*a.z + wv.w*a.w;
    a = r3[k4]; acc3 += wv.x*a.x + wv.y*a.y + wv.z*a.z + wv.w*a.w;
  }
  float bb = bias[j];
  float v;
  v = acc0 + bb; if (ACT) v = tanhf(v); out[(size_t)(b0 + bg + 0) * J + j] = v;
  v = acc1 + bb; if (ACT) v = tanhf(v); out[(size_t)(b0 + bg + 1) * J + j] = v;
  v = acc2 + bb; if (ACT) v = tanhf(v); out[(size_t)(b0 + bg + 2) * J + j] = v;
  v = acc3 + bb; if (ACT) v = tanhf(v); out[(size_t)(b0 + bg + 3) * J + j] = v;
}

// ---------------------------------------------------------------------------
// d_proj = sent @ wd^T + bd  via split-bf16 MFMA (3 mfma per tile, fp32 acc)
// M=25600 N=512 K=1024. Block 128x128, BK=32, 256 thr = 4 waves of 64x64.
// v2: compact [128][32]-short LDS tiles with 16B-slot XOR swizzle
//     (slot' = slot ^ ((row>>1)&3)) -> conflict-free b128 reads AND writes;
//     double-buffered (64 KB), ONE barrier per K-step;
//     B staged via global_load_lds (pre-swizzled per-lane global source,
//     linear LDS dest); A reg-staged with fused fp32->hi/lo-bf16 convert,
//     loads issued before the MFMA block so latency hides under compute.
constexpr int NSTEP = Kn / 32;   // 32

__launch_bounds__(256)
__global__ void k_dproj_mfma(const float* __restrict__ A, const ushort* __restrict__ Whi,
                             const ushort* __restrict__ Wlo, const float* __restrict__ bias,
                             float* __restrict__ C) {
  // 4 operands x 2 buffers x 128 rows x 32 shorts = 64 KB
  __shared__ __align__(16) ushort sAh[2][128 * 32];
  __shared__ __align__(16) ushort sAl[2][128 * 32];
  __shared__ __align__(16) ushort sBh[2][128 * 32];
  __shared__ __align__(16) ushort sBl[2][128 * 32];

  // XCD-chunked bijective swizzle: 800 blocks, 8 XCDs, 100 blocks each.
  // XCD x gets wg = x*100..x*100+99 -> one B n-slice (512 KB) reused 100x in its L2.
  const int bid = blockIdx.x;
  const int wg  = (bid & 7) * 100 + (bid >> 3);
  const int m0  = (wg % 200) * 128;
  const int n0  = (wg / 200) * 128;

  const int tid  = threadIdx.x;
  const int wave = tid >> 6, lane = tid & 63;
  const int wy = (wave >> 1) * 64, wx = (wave & 1) * 64;
  const int lm = lane & 15, lq = lane >> 4;      // tile row / k-quad

  // fragment-read swizzled slot: logical slot lq at row (16-aligned base + lm)
  // q(row) = (row>>1)&3 = (lm>>1)&3  (bases are multiples of 16)
  const int fs = (lq ^ ((lm >> 1) & 3)) * 8;     // shorts

  // ---- A staging geometry: thread t covers row sr, logical slots sb, sb+1
  const int sr = tid >> 1;
  const int sb = (tid & 1) * 2;
  const int qr = (sr >> 1) & 3;
  const int ps0 = (sr * 32) + (((sb + 0) ^ qr) * 8);
  const int ps1 = (sr * 32) + (((sb + 1) ^ qr) * 8);
  const float* Ap = A + (size_t)(m0 + sr) * Kn + sb * 8;

  // ---- B DMA geometry: per wave, 2 calls per half. Linear LDS slot
  // S = (wave*2+j)*64 + lane ; physical (row=S>>2, sp=S&3) must receive
  // logical slot c = sp ^ q(row)  ->  pre-swizzle the GLOBAL source.
  const int S0 = (wave * 2 + 0) * 64 + lane;
  const int S1 = (wave * 2 + 1) * 64 + lane;
  const int r0 = S0 >> 2, r1 = S1 >> 2;
  const int c0 = ((S0 & 3) ^ ((r0 >> 1) & 3)) * 8;
  const int c1 = ((S1 & 3) ^ ((r1 >> 1) & 3)) * 8;
  const ushort* Bh0 = Whi + (size_t)(n0 + r0) * Kn + c0;
  const ushort* Bh1 = Whi + (size_t)(n0 + r1) * Kn + c1;
  const ushort* Bl0 = Wlo + (size_t)(n0 + r0) * Kn + c0;
  const ushort* Bl1 = Wlo + (size_t)(n0 + r1) * Kn + c1;
  const int ldsS0 = (wave * 2 + 0) * 512;        // shorts (=64 lanes * 8 shorts)
  const int ldsS1 = (wave * 2 + 1) * 512;

  f32x4 acc[4][4] = {};

  // ---- prologue: stage step 0 into buffer 0
  {
    gld_lds16(Bh0, &sBh[0][ldsS0]); gld_lds16(Bh1, &sBh[0][ldsS1]);
    gld_lds16(Bl0, &sBl[0][ldsS0]); gld_lds16(Bl1, &sBl[0][ldsS1]);
    float4 av[4];
    #pragma unroll
    for (int i = 0; i < 4; ++i) av[i] = ((const float4*)Ap)[i];
    ushort8v h0, l0, h1, l1;
    cvt8(av[0], av[1], h0, l0);
    cvt8(av[2], av[3], h1, l1);
    asm volatile("s_waitcnt vmcnt(0)" ::: "memory");   // B-DMA landed
    *(ushort8v*)&sAh[0][ps0] = h0;  *(ushort8v*)&sAl[0][ps0] = l0;
    *(ushort8v*)&sAh[0][ps1] = h1;  *(ushort8v*)&sAl[0][ps1] = l1;
  }

  for (int ks = 0; ks < NSTEP; ++ks) {
    const int cur = ks & 1, nxt = cur ^ 1;
    __syncthreads();   // buf[cur] ready; all reads of buf[nxt] (step ks-1) done

    const int kn = (ks + 1) * 32;
    const bool pf = (ks + 1 < NSTEP);
    float4 av[4];
    if (pf) {
      // issue next-step loads FIRST; they fly under the MFMA block below
      gld_lds16(Bh0 + kn, &sBh[nxt][ldsS0]); gld_lds16(Bh1 + kn, &sBh[nxt][ldsS1]);
      gld_lds16(Bl0 + kn, &sBl[nxt][ldsS0]); gld_lds16(Bl1 + kn, &sBl[nxt][ldsS1]);
      #pragma unroll
      for (int i = 0; i < 4; ++i) av[i] = ((const float4*)(Ap + kn))[i];
    }

    bf16x8 ah[4], al[4], bh[4], bl[4];
    #pragma unroll
    for (int mi = 0; mi < 4; ++mi) {
      const int o = (wy + mi * 16 + lm) * 32 + fs;
      ah[mi] = *(const bf16x8*)&sAh[cur][o];
      al[mi] = *(const bf16x8*)&sAl[cur][o];
    }
    #pragma unroll
    for (int ni = 0; ni < 4; ++ni) {
      const int o = (wx + ni * 16 + lm) * 32 + fs;
      bh[ni] = *(const bf16x8*)&sBh[cur][o];
      bl[ni] = *(const bf16x8*)&sBl[cur][o];
    }
    #pragma unroll
    for (int mi = 0; mi < 4; ++mi)
      #pragma unroll
      for (int ni = 0; ni < 4; ++ni) {
        acc[mi][ni] = __builtin_amdgcn_mfma_f32_16x16x32_bf16(ah[mi], bh[ni], acc[mi][ni], 0, 0, 0);
        acc[mi][ni] = __builtin_amdgcn_mfma_f32_16x16x32_bf16(ah[mi], bl[ni], acc[mi][ni], 0, 0, 0);
        acc[mi][ni] = __builtin_amdgcn_mfma_f32_16x16x32_bf16(al[mi], bh[ni], acc[mi][ni], 0, 0, 0);
      }

    if (pf) {
      ushort8v h0, l0, h1, l1;
      cvt8(av[0], av[1], h0, l0);
      cvt8(av[2], av[3], h1, l1);
      asm volatile("s_waitcnt vmcnt(0)" ::: "memory");  // A regs + B-DMA complete
      *(ushort8v*)&sAh[nxt][ps0] = h0;  *(ushort8v*)&sAl[nxt][ps0] = l0;
      *(ushort8v*)&sAh[nxt][ps1] = h1;  *(ushort8v*)&sAl[nxt][ps1] = l1;
    }
  }

  // epilogue: D[row=lq*4+r][col=lm] per 16x16 tile
  #pragma unroll
  for (int ni = 0; ni < 4; ++ni) {
    int col = n0 + wx + ni * 16 + lm;
    float bb = bias[col];
    #pragma unroll
    for (int mi = 0; mi < 4; ++mi) {
      int rbase = m0 + wy + mi * 16 + lq * 4;
      #pragma unroll
      for (int r = 0; r < 4; ++r)
        C[(size_t)(rbase + r) * Nn + col] = acc[mi][ni][r] + bb;
    }
  }
}

// ---------------------------------------------------------------------------
// GRU pointwise: h = (1-z)*n + z*h
__global__ void k_gru_pw(const float* __restrict__ gx, const float* __restrict__ gh,
                         float* __restrict__ h) {
  int i = blockIdx.x * 256 + threadIdx.x;        // 65536
  int b = i >> 9, j = i & 511;
  const float* gxb = gx + (size_t)b * G3n;
  const float* ghb = gh + (size_t)b * G3n;
  float rg = 1.f / (1.f + expf(-(gxb[j] + ghb[j])));
  float zg = 1.f / (1.f + expf(-(gxb[512 + j] + ghb[512 + j])));
  float ng = tanhf(gxb[1024 + j] + rg * ghb[1024 + j]);
  h[i] = (1.f - zg) * ng + zg * h[i];
}

// ---------------------------------------------------------------------------
// score[b,l] = sum_a tanh(q[b,a] + dproj[b*L+l, a]) * ws[a] + bs ; apply mask
__launch_bounds__(256)
__global__ void k_score(const float* __restrict__ dproj, const float* __restrict__ q,
                        const float* __restrict__ wsv, const float* __restrict__ bsv,
                        const int* __restrict__ mask, float* __restrict__ scoresf,
                        float* __restrict__ outScores, int t) {
  int w = blockIdx.x * 4 + (threadIdx.x >> 6);   // 0..25599
  int lane = threadIdx.x & 63;
  int b = w / Ln, l = w % Ln;
  const float4* dp4 = (const float4*)(dproj + (size_t)w * Nn);
  const float4* q4  = (const float4*)(q + (size_t)b * Nn);
  const float4* ws4 = (const float4*)wsv;

  float sum = 0.f;
  #pragma unroll
  for (int i = 0; i < 2; ++i) {
    int idx = lane + i * 64;                     // 128 float4 per row
    float4 d = dp4[idx], qq = q4[idx], wv = ws4[idx];
    sum += tanhf(qq.x + d.x) * wv.x + tanhf(qq.y + d.y) * wv.y
         + tanhf(qq.z + d.z) * wv.z + tanhf(qq.w + d.w) * wv.w;
  }
  #pragma unroll
  for (int off = 32; off > 0; off >>= 1) sum += __shfl_xor(sum, off, 64);

  if (lane == 0) {
    float v = sum + bsv[0];
    if (mask[w]) v = -1000000.0f;
    scoresf[w] = v;
    outScores[(size_t)b * (Tn * Ln) + t * Ln + l] = v;
  }
}

// ---------------------------------------------------------------------------
// per-batch argmax (first-index tie-break), update mask, gather selected row
__launch_bounds__(256)
__global__ void k_argmax(const float* __restrict__ scoresf, const float* __restrict__ sent,
                         float* __restrict__ s_row, int* __restrict__ mask,
                         float* __restrict__ outSel, int t) {
  int b = blockIdx.x;
  __shared__ int s_idx;
  int tid = threadIdx.x;
  if (tid < 64) {
    const float* sc = scoresf + (size_t)b * Ln;
    float best = -3.0e38f; int bi = 0;
    for (int l = tid; l < Ln; l += 64) {
      float v = sc[l];
      if (v > best) { best = v; bi = l; }        // increasing l: strict > keeps first
    }
    #pragma unroll
    for (int off = 32; off > 0; off >>= 1) {
      float ov = __shfl_down(best, off, 64);
      int   oi = __shfl_down(bi,   off, 64);
      if (ov > best || (ov == best && oi < bi)) { best = ov; bi = oi; }
    }
    if (tid == 0) s_idx = bi;
  }
  __syncthreads();
  int idx = s_idx;
  const float* src = sent + ((size_t)b * Ln + idx) * D2n;
  float* dstp = s_row + (size_t)b * D2n;
  int k = tid * 4;                               // 256 threads x 4 = 1024
  *(float4*)(dstp + k) = *(const float4*)(src + k);
  if (tid == 0) {
    mask[b * Ln + idx] = 1;
    outSel[(size_t)b * Tn + t] = (float)idx;
  }
}

// ---------------------------------------------------------------------------
extern "C" void kernel_launch(void* const* d_in, const int* in_sizes, int n_in,
                              void* d_out, int out_size, void* d_ws, size_t ws_size,
                              hipStream_t stream) {
  const float* sent = (const float*)d_in[0];
  const float* h0_w = (const float*)d_in[1];
  const float* h0_b = (const float*)d_in[2];
  const float* w_ih = (const float*)d_in[3];
  const float* w_hh = (const float*)d_in[4];
  const float* b_ih = (const float*)d_in[5];
  const float* b_hh = (const float*)d_in[6];
  const float* wq   = (const float*)d_in[7];
  const float* bq   = (const float*)d_in[8];
  const float* wd   = (const float*)d_in[9];
  const float* bd   = (const float*)d_in[10];
  const float* wsv  = (const float*)d_in[11];
  const float* bsv  = (const float*)d_in[12];

  float* wsf     = (float*)d_ws;
  float* d_proj  = wsf;                       // 25600*512 = 13107200
  float* s_row   = d_proj + 13107200;         // 128*1024
  float* h       = s_row + 131072;            // 128*512
  float* gx      = h + 65536;                 // 128*1536
  float* gh      = gx + 196608;               // 128*1536
  float* lastb   = gh + 196608;               // 128*512
  float* q       = lastb + 65536;             // 128*512
  float* scoresf = q + 65536;                 // 128*200
  int*   mask    = (int*)(scoresf + 25600);   // 128*200 ints
  ushort* Whi    = (ushort*)(mask + 25600);   // 512*1024 shorts
  ushort* Wlo    = Whi + 524288;              // 512*1024 shorts

  float* outScores = (float*)d_out;                       // (B, T, L) fp32
  float* outSel    = outScores + (size_t)Bn * Tn * Ln;    // (B, T) fp32

  hipMemsetAsync(s_row, 0, 131072 * sizeof(float), stream);       // s_prev(t=0) = 0
  hipMemsetAsync(mask, 0, 25600 * sizeof(int), stream);

  k_gather_lastb<<<256, 256, 0, stream>>>(sent, lastb);
  k_small_gemm<512, 1><<<dim3(8, 8), 256, 0, stream>>>(lastb, h0_w, h0_b, h, 512);
  k_splitW<<<512, 256, 0, stream>>>(wd, Whi, Wlo);        // 512*1024/4 = 131072 float4
  k_dproj_mfma<<<800, 256, 0, stream>>>(sent, Whi, Wlo, bd, d_proj);

  for (int t = 0; t < Tn; ++t) {
    k_small_gemm<1024, 0><<<dim3(24, 8), 256, 0, stream>>>(s_row, w_ih, b_ih, gx, G3n);
    k_small_gemm<512, 0><<<dim3(24, 8), 256, 0, stream>>>(h, w_hh, b_hh, gh, G3n);
    k_gru_pw<<<256, 256, 0, stream>>>(gx, gh, h);
    k_small_gemm<512, 0><<<dim3(8, 8), 256, 0, stream>>>(h, wq, bq, q, 512);
    k_score<<<6400, 256, 0, stream>>>(d_proj, q, wsv, bsv, mask, scoresf, outScores, t);
    k_argmax<<<128, 256, 0, stream>>>(scoresf, sent, s_row, mask, outSel, t);
  }
}

// Round 2
// 626.517 us; speedup vs baseline: 1.0431x; 1.0431x over previous
//
#include <hip/hip_runtime.h>
#include <hip/hip_bf16.h>

// Problem constants
constexpr int Bn  = 128;   // batch
constexpr int Ln  = 200;   // sentences
constexpr int D2n = 1024;  // 2*SH
constexpr int G3n = 1536;  // 3*EH
constexpr int Tn  = 3;
constexpr int Nn  = 512;   // A (attention dim) == d_proj cols
constexpr int Kn  = 1024;  // d_proj K

typedef unsigned short ushort;
typedef float f32x4 __attribute__((ext_vector_type(4)));
typedef __bf16 bf16x8 __attribute__((ext_vector_type(8)));
typedef ushort ushort8v __attribute__((ext_vector_type(8)));

__device__ __forceinline__ ushort f2bf(float f) {   // RNE float->bf16
  unsigned u = __float_as_uint(f);
  unsigned r = (u + 0x7fffu + ((u >> 16) & 1u)) >> 16;
  return (ushort)r;
}
__device__ __forceinline__ float bf2f(ushort h) {
  return __uint_as_float(((unsigned)h) << 16);
}

__device__ __forceinline__ void gld_lds16(const ushort* g, ushort* l) {
  __builtin_amdgcn_global_load_lds(
      (const __attribute__((address_space(1))) unsigned int*)g,
      (__attribute__((address_space(3))) unsigned int*)l, 16, 0, 0);
}

__device__ __forceinline__ void cvt8(const float4 a, const float4 b,
                                     ushort8v& h, ushort8v& l) {
  float f[8] = {a.x, a.y, a.z, a.w, b.x, b.y, b.z, b.w};
  #pragma unroll
  for (int i = 0; i < 8; ++i) {
    ushort hi = f2bf(f[i]);
    h[i] = hi;
    l[i] = f2bf(f[i] - bf2f(hi));
  }
}

// ---------------------------------------------------------------------------
// gather last_back = sent[:, 0, 512:1024]
__global__ void k_gather_lastb(const float* __restrict__ sent, float* __restrict__ lastb) {
  int i = blockIdx.x * 256 + threadIdx.x;        // 65536 = 128*512
  int b = i >> 9, k = i & 511;
  lastb[i] = sent[(size_t)b * (Ln * D2n) + 512 + k];
}

// ---------------------------------------------------------------------------
// split W (fp32, N elements) into hi/lo bf16
__global__ void k_splitW(const float* __restrict__ W, ushort* __restrict__ hi,
                         ushort* __restrict__ lo) {
  int i = blockIdx.x * 256 + threadIdx.x;        // element/4
  float4 v = ((const float4*)W)[i];
  ushort4 h, l;
  h.x = f2bf(v.x); l.x = f2bf(v.x - bf2f(h.x));
  h.y = f2bf(v.y); l.y = f2bf(v.y - bf2f(h.y));
  h.z = f2bf(v.z); l.z = f2bf(v.z - bf2f(h.z));
  h.w = f2bf(v.w); l.w = f2bf(v.w - bf2f(h.w));
  ((ushort4*)hi)[i] = h;
  ((ushort4*)lo)[i] = l;
}

// ---------------------------------------------------------------------------
// small GEMM: out[b,j] = act(bias[j] + sum_k in[b,k] * W[j,k])
template<int K, int ACT>
__launch_bounds__(256)
__global__ void k_small_gemm(const float* __restrict__ in, const float* __restrict__ W,
                             const float* __restrict__ bias, float* __restrict__ out, int J) {
  __shared__ float s[16 * K];
  const int b0 = blockIdx.y * 16;
  const int jl = threadIdx.x & 63;
  const int j  = blockIdx.x * 64 + jl;
  const int bg = (threadIdx.x >> 6) * 4;         // 0,4,8,12

  const float4* inp4 = (const float4*)(in + (size_t)b0 * K);
  float4* s4 = (float4*)s;
  for (int i = threadIdx.x; i < 4 * K; i += 256) s4[i] = inp4[i];
  __syncthreads();

  const float4* w4 = (const float4*)(W + (size_t)j * K);
  const float4* r0 = (const float4*)(s + (size_t)(bg + 0) * K);
  const float4* r1 = (const float4*)(s + (size_t)(bg + 1) * K);
  const float4* r2 = (const float4*)(s + (size_t)(bg + 2) * K);
  const float4* r3 = (const float4*)(s + (size_t)(bg + 3) * K);

  float acc0 = 0.f, acc1 = 0.f, acc2 = 0.f, acc3 = 0.f;
  #pragma unroll 4
  for (int k4 = 0; k4 < K / 4; ++k4) {
    float4 wv = w4[k4];
    float4 a;
    a = r0[k4]; acc0 += wv.x*a.x + wv.y*a.y + wv.z*a.z + wv.w*a.w;
    a = r1[k4]; acc1 += wv.x*a.x + wv.y*a.y + wv.z*a.z + wv.w*a.w;
    a = r2[k4]; acc2 += wv.x*a.x + wv.y*a.y + wv.z*a.z + wv.w*a.w;
    a = r3[k4]; acc3 += wv.x*a.x + wv.y*a.y + wv.z*a.z + wv.w*a.w;
  }
  float bb = bias[j];
  float v;
  v = acc0 + bb; if (ACT) v = tanhf(v); out[(size_t)(b0 + bg + 0) * J + j] = v;
  v = acc1 + bb; if (ACT) v = tanhf(v); out[(size_t)(b0 + bg + 1) * J + j] = v;
  v = acc2 + bb; if (ACT) v = tanhf(v); out[(size_t)(b0 + bg + 2) * J + j] = v;
  v = acc3 + bb; if (ACT) v = tanhf(v); out[(size_t)(b0 + bg + 3) * J + j] = v;
}

// ---------------------------------------------------------------------------
// d_proj = sent @ wd^T + bd  via split-bf16 MFMA (3 mfma per tile, fp32 acc)
// M=25600 N=512 K=1024. Block 128x128, BK=32, 256 thr = 4 waves of 64x64.
// v3: same pipeline as v2 (compact swizzled LDS, conflict-free b128 r/w,
//     double-buffered, ONE barrier per K-step, B via global_load_lds with
//     pre-swizzled global source, A reg-staged w/ fused fp32->hi/lo cvt)
//     BUT block mapping reverted to the v0 geometry: m = bid%200, n = bid/200.
//     Since 200 % 8 == 0, the 4 blocks sharing an A m-tile (bid = m, m+200,
//     m+400, m+600) all land on the SAME XCD and are co-resident -> A-tile
//     fetched once (v2's chunked swizzle split them across 4 L2s: FETCH
//     116->209 MB, ~900cyc misses instead of ~200cyc L2 hits, -26% perf).
constexpr int NSTEP = Kn / 32;   // 32

__launch_bounds__(256)
__global__ void k_dproj_mfma(const float* __restrict__ A, const ushort* __restrict__ Whi,
                             const ushort* __restrict__ Wlo, const float* __restrict__ bias,
                             float* __restrict__ C) {
  // 4 operands x 2 buffers x 128 rows x 32 shorts = 64 KB
  __shared__ __align__(16) ushort sAh[2][128 * 32];
  __shared__ __align__(16) ushort sAl[2][128 * 32];
  __shared__ __align__(16) ushort sBh[2][128 * 32];
  __shared__ __align__(16) ushort sBl[2][128 * 32];

  const int bid = blockIdx.x;
  const int m0  = (bid % 200) * 128;
  const int n0  = (bid / 200) * 128;

  const int tid  = threadIdx.x;
  const int wave = tid >> 6, lane = tid & 63;
  const int wy = (wave >> 1) * 64, wx = (wave & 1) * 64;
  const int lm = lane & 15, lq = lane >> 4;      // tile row / k-quad

  // fragment-read swizzled slot: logical slot lq at row (16-aligned base + lm)
  // q(row) = (row>>1)&3 = (lm>>1)&3  (bases are multiples of 16)
  const int fs = (lq ^ ((lm >> 1) & 3)) * 8;     // shorts

  // ---- A staging geometry: thread t covers row sr, logical slots sb, sb+1
  const int sr = tid >> 1;
  const int sb = (tid & 1) * 2;
  const int qr = (sr >> 1) & 3;
  const int ps0 = (sr * 32) + (((sb + 0) ^ qr) * 8);
  const int ps1 = (sr * 32) + (((sb + 1) ^ qr) * 8);
  const float* Ap = A + (size_t)(m0 + sr) * Kn + sb * 8;

  // ---- B DMA geometry: per wave, 2 calls per half. Linear LDS slot
  // S = (wave*2+j)*64 + lane ; physical (row=S>>2, sp=S&3) must receive
  // logical slot c = sp ^ q(row)  ->  pre-swizzle the GLOBAL source.
  const int S0 = (wave * 2 + 0) * 64 + lane;
  const int S1 = (wave * 2 + 1) * 64 + lane;
  const int r0 = S0 >> 2, r1 = S1 >> 2;
  const int c0 = ((S0 & 3) ^ ((r0 >> 1) & 3)) * 8;
  const int c1 = ((S1 & 3) ^ ((r1 >> 1) & 3)) * 8;
  const ushort* Bh0 = Whi + (size_t)(n0 + r0) * Kn + c0;
  const ushort* Bh1 = Whi + (size_t)(n0 + r1) * Kn + c1;
  const ushort* Bl0 = Wlo + (size_t)(n0 + r0) * Kn + c0;
  const ushort* Bl1 = Wlo + (size_t)(n0 + r1) * Kn + c1;
  const int ldsS0 = (wave * 2 + 0) * 512;        // shorts (=64 lanes * 8 shorts)
  const int ldsS1 = (wave * 2 + 1) * 512;

  f32x4 acc[4][4] = {};

  // ---- prologue: stage step 0 into buffer 0
  {
    gld_lds16(Bh0, &sBh[0][ldsS0]); gld_lds16(Bh1, &sBh[0][ldsS1]);
    gld_lds16(Bl0, &sBl[0][ldsS0]); gld_lds16(Bl1, &sBl[0][ldsS1]);
    float4 av[4];
    #pragma unroll
    for (int i = 0; i < 4; ++i) av[i] = ((const float4*)Ap)[i];
    ushort8v h0, l0, h1, l1;
    cvt8(av[0], av[1], h0, l0);
    cvt8(av[2], av[3], h1, l1);
    asm volatile("s_waitcnt vmcnt(0)" ::: "memory");   // B-DMA landed
    *(ushort8v*)&sAh[0][ps0] = h0;  *(ushort8v*)&sAl[0][ps0] = l0;
    *(ushort8v*)&sAh[0][ps1] = h1;  *(ushort8v*)&sAl[0][ps1] = l1;
  }

  for (int ks = 0; ks < NSTEP; ++ks) {
    const int cur = ks & 1, nxt = cur ^ 1;
    __syncthreads();   // buf[cur] ready; all reads of buf[nxt] (step ks-1) done

    const int kn = (ks + 1) * 32;
    const bool pf = (ks + 1 < NSTEP);
    float4 av[4];
    if (pf) {
      // issue next-step loads FIRST; they fly under the MFMA block below
      gld_lds16(Bh0 + kn, &sBh[nxt][ldsS0]); gld_lds16(Bh1 + kn, &sBh[nxt][ldsS1]);
      gld_lds16(Bl0 + kn, &sBl[nxt][ldsS0]); gld_lds16(Bl1 + kn, &sBl[nxt][ldsS1]);
      #pragma unroll
      for (int i = 0; i < 4; ++i) av[i] = ((const float4*)(Ap + kn))[i];
    }

    bf16x8 ah[4], al[4], bh[4], bl[4];
    #pragma unroll
    for (int mi = 0; mi < 4; ++mi) {
      const int o = (wy + mi * 16 + lm) * 32 + fs;
      ah[mi] = *(const bf16x8*)&sAh[cur][o];
      al[mi] = *(const bf16x8*)&sAl[cur][o];
    }
    #pragma unroll
    for (int ni = 0; ni < 4; ++ni) {
      const int o = (wx + ni * 16 + lm) * 32 + fs;
      bh[ni] = *(const bf16x8*)&sBh[cur][o];
      bl[ni] = *(const bf16x8*)&sBl[cur][o];
    }
    #pragma unroll
    for (int mi = 0; mi < 4; ++mi)
      #pragma unroll
      for (int ni = 0; ni < 4; ++ni) {
        acc[mi][ni] = __builtin_amdgcn_mfma_f32_16x16x32_bf16(ah[mi], bh[ni], acc[mi][ni], 0, 0, 0);
        acc[mi][ni] = __builtin_amdgcn_mfma_f32_16x16x32_bf16(ah[mi], bl[ni], acc[mi][ni], 0, 0, 0);
        acc[mi][ni] = __builtin_amdgcn_mfma_f32_16x16x32_bf16(al[mi], bh[ni], acc[mi][ni], 0, 0, 0);
      }

    if (pf) {
      ushort8v h0, l0, h1, l1;
      cvt8(av[0], av[1], h0, l0);
      cvt8(av[2], av[3], h1, l1);
      asm volatile("s_waitcnt vmcnt(0)" ::: "memory");  // A regs + B-DMA complete
      *(ushort8v*)&sAh[nxt][ps0] = h0;  *(ushort8v*)&sAl[nxt][ps0] = l0;
      *(ushort8v*)&sAh[nxt][ps1] = h1;  *(ushort8v*)&sAl[nxt][ps1] = l1;
    }
  }

  // epilogue: D[row=lq*4+r][col=lm] per 16x16 tile
  #pragma unroll
  for (int ni = 0; ni < 4; ++ni) {
    int col = n0 + wx + ni * 16 + lm;
    float bb = bias[col];
    #pragma unroll
    for (int mi = 0; mi < 4; ++mi) {
      int rbase = m0 + wy + mi * 16 + lq * 4;
      #pragma unroll
      for (int r = 0; r < 4; ++r)
        C[(size_t)(rbase + r) * Nn + col] = acc[mi][ni][r] + bb;
    }
  }
}

// ---------------------------------------------------------------------------
// GRU pointwise: h = (1-z)*n + z*h
__global__ void k_gru_pw(const float* __restrict__ gx, const float* __restrict__ gh,
                         float* __restrict__ h) {
  int i = blockIdx.x * 256 + threadIdx.x;        // 65536
  int b = i >> 9, j = i & 511;
  const float* gxb = gx + (size_t)b * G3n;
  const float* ghb = gh + (size_t)b * G3n;
  float rg = 1.f / (1.f + expf(-(gxb[j] + ghb[j])));
  float zg = 1.f / (1.f + expf(-(gxb[512 + j] + ghb[512 + j])));
  float ng = tanhf(gxb[1024 + j] + rg * ghb[1024 + j]);
  h[i] = (1.f - zg) * ng + zg * h[i];
}

// ---------------------------------------------------------------------------
// score[b,l] = sum_a tanh(q[b,a] + dproj[b*L+l, a]) * ws[a] + bs ; apply mask
__launch_bounds__(256)
__global__ void k_score(const float* __restrict__ dproj, const float* __restrict__ q,
                        const float* __restrict__ wsv, const float* __restrict__ bsv,
                        const int* __restrict__ mask, float* __restrict__ scoresf,
                        float* __restrict__ outScores, int t) {
  int w = blockIdx.x * 4 + (threadIdx.x >> 6);   // 0..25599
  int lane = threadIdx.x & 63;
  int b = w / Ln, l = w % Ln;
  const float4* dp4 = (const float4*)(dproj + (size_t)w * Nn);
  const float4* q4  = (const float4*)(q + (size_t)b * Nn);
  const float4* ws4 = (const float4*)wsv;

  float sum = 0.f;
  #pragma unroll
  for (int i = 0; i < 2; ++i) {
    int idx = lane + i * 64;                     // 128 float4 per row
    float4 d = dp4[idx], qq = q4[idx], wv = ws4[idx];
    sum += tanhf(qq.x + d.x) * wv.x + tanhf(qq.y + d.y) * wv.y
         + tanhf(qq.z + d.z) * wv.z + tanhf(qq.w + d.w) * wv.w;
  }
  #pragma unroll
  for (int off = 32; off > 0; off >>= 1) sum += __shfl_xor(sum, off, 64);

  if (lane == 0) {
    float v = sum + bsv[0];
    if (mask[w]) v = -1000000.0f;
    scoresf[w] = v;
    outScores[(size_t)b * (Tn * Ln) + t * Ln + l] = v;
  }
}

// ---------------------------------------------------------------------------
// per-batch argmax (first-index tie-break), update mask, gather selected row
__launch_bounds__(256)
__global__ void k_argmax(const float* __restrict__ scoresf, const float* __restrict__ sent,
                         float* __restrict__ s_row, int* __restrict__ mask,
                         float* __restrict__ outSel, int t) {
  int b = blockIdx.x;
  __shared__ int s_idx;
  int tid = threadIdx.x;
  if (tid < 64) {
    const float* sc = scoresf + (size_t)b * Ln;
    float best = -3.0e38f; int bi = 0;
    for (int l = tid; l < Ln; l += 64) {
      float v = sc[l];
      if (v > best) { best = v; bi = l; }        // increasing l: strict > keeps first
    }
    #pragma unroll
    for (int off = 32; off > 0; off >>= 1) {
      float ov = __shfl_down(best, off, 64);
      int   oi = __shfl_down(bi,   off, 64);
      if (ov > best || (ov == best && oi < bi)) { best = ov; bi = oi; }
    }
    if (tid == 0) s_idx = bi;
  }
  __syncthreads();
  int idx = s_idx;
  const float* src = sent + ((size_t)b * Ln + idx) * D2n;
  float* dstp = s_row + (size_t)b * D2n;
  int k = tid * 4;                               // 256 threads x 4 = 1024
  *(float4*)(dstp + k) = *(const float4*)(src + k);
  if (tid == 0) {
    mask[b * Ln + idx] = 1;
    outSel[(size_t)b * Tn + t] = (float)idx;
  }
}

// ---------------------------------------------------------------------------
extern "C" void kernel_launch(void* const* d_in, const int* in_sizes, int n_in,
                              void* d_out, int out_size, void* d_ws, size_t ws_size,
                              hipStream_t stream) {
  const float* sent = (const float*)d_in[0];
  const float* h0_w = (const float*)d_in[1];
  const float* h0_b = (const float*)d_in[2];
  const float* w_ih = (const float*)d_in[3];
  const float* w_hh = (const float*)d_in[4];
  const float* b_ih = (const float*)d_in[5];
  const float* b_hh = (const float*)d_in[6];
  const float* wq   = (const float*)d_in[7];
  const float* bq   = (const float*)d_in[8];
  const float* wd   = (const float*)d_in[9];
  const float* bd   = (const float*)d_in[10];
  const float* wsv  = (const float*)d_in[11];
  const float* bsv  = (const float*)d_in[12];

  float* wsf     = (float*)d_ws;
  float* d_proj  = wsf;                       // 25600*512 = 13107200
  float* s_row   = d_proj + 13107200;         // 128*1024
  float* h       = s_row + 131072;            // 128*512
  float* gx      = h + 65536;                 // 128*1536
  float* gh      = gx + 196608;               // 128*1536
  float* lastb   = gh + 196608;               // 128*512
  float* q       = lastb + 65536;             // 128*512
  float* scoresf = q + 65536;                 // 128*200
  int*   mask    = (int*)(scoresf + 25600);   // 128*200 ints
  ushort* Whi    = (ushort*)(mask + 25600);   // 512*1024 shorts
  ushort* Wlo    = Whi + 524288;              // 512*1024 shorts

  float* outScores = (float*)d_out;                       // (B, T, L) fp32
  float* outSel    = outScores + (size_t)Bn * Tn * Ln;    // (B, T) fp32

  hipMemsetAsync(s_row, 0, 131072 * sizeof(float), stream);       // s_prev(t=0) = 0
  hipMemsetAsync(mask, 0, 25600 * sizeof(int), stream);

  k_gather_lastb<<<256, 256, 0, stream>>>(sent, lastb);
  k_small_gemm<512, 1><<<dim3(8, 8), 256, 0, stream>>>(lastb, h0_w, h0_b, h, 512);
  k_splitW<<<512, 256, 0, stream>>>(wd, Whi, Wlo);        // 512*1024/4 = 131072 float4
  k_dproj_mfma<<<800, 256, 0, stream>>>(sent, Whi, Wlo, bd, d_proj);

  for (int t = 0; t < Tn; ++t) {
    k_small_gemm<1024, 0><<<dim3(24, 8), 256, 0, stream>>>(s_row, w_ih, b_ih, gx, G3n);
    k_small_gemm<512, 0><<<dim3(24, 8), 256, 0, stream>>>(h, w_hh, b_hh, gh, G3n);
    k_gru_pw<<<256, 256, 0, stream>>>(gx, gh, h);
    k_small_gemm<512, 0><<<dim3(8, 8), 256, 0, stream>>>(h, wq, bq, q, 512);
    k_score<<<6400, 256, 0, stream>>>(d_proj, q, wsv, bsv, mask, scoresf, outScores, t);
    k_argmax<<<128, 256, 0, stream>>>(scoresf, sent, s_row, mask, outSel, t);
  }
}

// Round 3
// 619.316 us; speedup vs baseline: 1.0552x; 1.0116x over previous
//
#include <hip/hip_runtime.h>
#include <hip/hip_bf16.h>

// Problem constants
constexpr int Bn  = 128;   // batch
constexpr int Ln  = 200;   // sentences
constexpr int D2n = 1024;  // 2*SH
constexpr int G3n = 1536;  // 3*EH
constexpr int Tn  = 3;
constexpr int Nn  = 512;   // A (attention dim) == d_proj cols
constexpr int Kn  = 1024;  // d_proj K

typedef unsigned short ushort;
typedef float f32x4 __attribute__((ext_vector_type(4)));
typedef __bf16 bf16x8 __attribute__((ext_vector_type(8)));

__device__ __forceinline__ ushort f2bf(float f) {   // RNE float->bf16
  unsigned u = __float_as_uint(f);
  unsigned r = (u + 0x7fffu + ((u >> 16) & 1u)) >> 16;
  return (ushort)r;
}
__device__ __forceinline__ float bf2f(ushort h) {
  return __uint_as_float(((unsigned)h) << 16);
}

__device__ __forceinline__ void gld_lds16(const ushort* g, ushort* l) {
  __builtin_amdgcn_global_load_lds(
      (const __attribute__((address_space(1))) unsigned int*)g,
      (__attribute__((address_space(3))) unsigned int*)l, 16, 0, 0);
}

// ---------------------------------------------------------------------------
// gather last_back = sent[:, 0, 512:1024]
__global__ void k_gather_lastb(const float* __restrict__ sent, float* __restrict__ lastb) {
  int i = blockIdx.x * 256 + threadIdx.x;        // 65536 = 128*512
  int b = i >> 9, k = i & 511;
  lastb[i] = sent[(size_t)b * (Ln * D2n) + 512 + k];
}

// ---------------------------------------------------------------------------
// split fp32 -> hi/lo bf16 (used for both wd [512x1024] and sent [25600x1024])
__global__ void k_split(const float* __restrict__ W, ushort* __restrict__ hi,
                        ushort* __restrict__ lo) {
  int i = blockIdx.x * 256 + threadIdx.x;        // float4 index
  float4 v = ((const float4*)W)[i];
  ushort4 h, l;
  h.x = f2bf(v.x); l.x = f2bf(v.x - bf2f(h.x));
  h.y = f2bf(v.y); l.y = f2bf(v.y - bf2f(h.y));
  h.z = f2bf(v.z); l.z = f2bf(v.z - bf2f(h.z));
  h.w = f2bf(v.w); l.w = f2bf(v.w - bf2f(h.w));
  ((ushort4*)hi)[i] = h;
  ((ushort4*)lo)[i] = l;
}

// ---------------------------------------------------------------------------
// small GEMM: out[b,j] = act(bias[j] + sum_k in[b,k] * W[j,k])
template<int K, int ACT>
__launch_bounds__(256)
__global__ void k_small_gemm(const float* __restrict__ in, const float* __restrict__ W,
                             const float* __restrict__ bias, float* __restrict__ out, int J) {
  __shared__ float s[16 * K];
  const int b0 = blockIdx.y * 16;
  const int jl = threadIdx.x & 63;
  const int j  = blockIdx.x * 64 + jl;
  const int bg = (threadIdx.x >> 6) * 4;         // 0,4,8,12

  const float4* inp4 = (const float4*)(in + (size_t)b0 * K);
  float4* s4 = (float4*)s;
  for (int i = threadIdx.x; i < 4 * K; i += 256) s4[i] = inp4[i];
  __syncthreads();

  const float4* w4 = (const float4*)(W + (size_t)j * K);
  const float4* r0 = (const float4*)(s + (size_t)(bg + 0) * K);
  const float4* r1 = (const float4*)(s + (size_t)(bg + 1) * K);
  const float4* r2 = (const float4*)(s + (size_t)(bg + 2) * K);
  const float4* r3 = (const float4*)(s + (size_t)(bg + 3) * K);

  float acc0 = 0.f, acc1 = 0.f, acc2 = 0.f, acc3 = 0.f;
  #pragma unroll 4
  for (int k4 = 0; k4 < K / 4; ++k4) {
    float4 wv = w4[k4];
    float4 a;
    a = r0[k4]; acc0 += wv.x*a.x + wv.y*a.y + wv.z*a.z + wv.w*a.w;
    a = r1[k4]; acc1 += wv.x*a.x + wv.y*a.y + wv.z*a.z + wv.w*a.w;
    a = r2[k4]; acc2 += wv.x*a.x + wv.y*a.y + wv.z*a.z + wv.w*a.w;
    a = r3[k4]; acc3 += wv.x*a.x + wv.y*a.y + wv.z*a.z + wv.w*a.w;
  }
  float bb = bias[j];
  float v;
  v = acc0 + bb; if (ACT) v = tanhf(v); out[(size_t)(b0 + bg + 0) * J + j] = v;
  v = acc1 + bb; if (ACT) v = tanhf(v); out[(size_t)(b0 + bg + 1) * J + j] = v;
  v = acc2 + bb; if (ACT) v = tanhf(v); out[(size_t)(b0 + bg + 2) * J + j] = v;
  v = acc3 + bb; if (ACT) v = tanhf(v); out[(size_t)(b0 + bg + 3) * J + j] = v;
}

// ---------------------------------------------------------------------------
// d_proj = sent @ wd^T + bd  via split-bf16 MFMA (3 mfma per tile, fp32 acc)
// M=25600 N=512 K=1024. Block 128x128, BK=32, 256 thr = 4 waves of 64x64.
// v4 (m97 structure): A pre-split to global bf16 hi/lo by k_split, so ALL four
//   operands stage via global_load_lds (zero staging VALU / ds_writes in the
//   loop). Single-buffered 32 KB LDS (5-block LDS cap; regs cap ~3 blocks/CU,
//   up from v3's 2), two barriers per K-step. XOR-swizzled 16B slots keep all
//   ds_read_b128 conflict-free (measured 0 in R1/R2). bid%200 mapping keeps
//   the 4 blocks sharing an A m-tile on one XCD (R1 lesson: FETCH 116 MB).
constexpr int NSTEP = Kn / 32;   // 32

__launch_bounds__(256)
__global__ void k_dproj_mfma(const ushort* __restrict__ Ahi, const ushort* __restrict__ Alo,
                             const ushort* __restrict__ Whi, const ushort* __restrict__ Wlo,
                             const float* __restrict__ bias, float* __restrict__ C) {
  // 4 operands x 128 rows x 32 shorts = 32 KB
  __shared__ __align__(16) ushort sAh[128 * 32];
  __shared__ __align__(16) ushort sAl[128 * 32];
  __shared__ __align__(16) ushort sBh[128 * 32];
  __shared__ __align__(16) ushort sBl[128 * 32];

  const int bid = blockIdx.x;
  const int m0  = (bid % 200) * 128;
  const int n0  = (bid / 200) * 128;

  const int tid  = threadIdx.x;
  const int wave = tid >> 6, lane = tid & 63;
  const int wy = (wave >> 1) * 64, wx = (wave & 1) * 64;
  const int lm = lane & 15, lq = lane >> 4;      // tile row / k-quad

  // fragment-read swizzled slot: logical slot lq at row (16-aligned base + lm)
  const int fs = (lq ^ ((lm >> 1) & 3)) * 8;     // shorts

  // ---- DMA geometry: 512 16B-slots per array, 2 per thread per array.
  // Linear LDS slot S -> physical (row=S>>2, slot=S&3) holds logical slot
  // (S&3)^q(row): pre-swizzle the GLOBAL source column.
  const int S0 = (wave * 2 + 0) * 64 + lane;
  const int S1 = (wave * 2 + 1) * 64 + lane;
  const int r0 = S0 >> 2, r1 = S1 >> 2;
  const int c0 = ((S0 & 3) ^ ((r0 >> 1) & 3)) * 8;
  const int c1 = ((S1 & 3) ^ ((r1 >> 1) & 3)) * 8;
  const ushort* pAh0 = Ahi + (size_t)(m0 + r0) * Kn + c0;
  const ushort* pAh1 = Ahi + (size_t)(m0 + r1) * Kn + c1;
  const ushort* pAl0 = Alo + (size_t)(m0 + r0) * Kn + c0;
  const ushort* pAl1 = Alo + (size_t)(m0 + r1) * Kn + c1;
  const ushort* pBh0 = Whi + (size_t)(n0 + r0) * Kn + c0;
  const ushort* pBh1 = Whi + (size_t)(n0 + r1) * Kn + c1;
  const ushort* pBl0 = Wlo + (size_t)(n0 + r0) * Kn + c0;
  const ushort* pBl1 = Wlo + (size_t)(n0 + r1) * Kn + c1;
  ushort* dA0 = &sAh[S0 * 8]; ushort* dA1 = &sAh[S1 * 8];
  ushort* dL0 = &sAl[S0 * 8]; ushort* dL1 = &sAl[S1 * 8];
  ushort* dB0 = &sBh[S0 * 8]; ushort* dB1 = &sBh[S1 * 8];
  ushort* dC0 = &sBl[S0 * 8]; ushort* dC1 = &sBl[S1 * 8];

  f32x4 acc[4][4] = {};

  for (int ks = 0; ks < NSTEP; ++ks) {
    const int ko = ks * 32;
    gld_lds16(pAh0 + ko, dA0); gld_lds16(pAh1 + ko, dA1);
    gld_lds16(pAl0 + ko, dL0); gld_lds16(pAl1 + ko, dL1);
    gld_lds16(pBh0 + ko, dB0); gld_lds16(pBh1 + ko, dB1);
    gld_lds16(pBl0 + ko, dC0); gld_lds16(pBl1 + ko, dC1);
    __syncthreads();   // implicit vmcnt(0): tile landed

    bf16x8 ah[4], al[4], bh[4], bl[4];
    #pragma unroll
    for (int mi = 0; mi < 4; ++mi) {
      const int o = (wy + mi * 16 + lm) * 32 + fs;
      ah[mi] = *(const bf16x8*)&sAh[o];
      al[mi] = *(const bf16x8*)&sAl[o];
    }
    #pragma unroll
    for (int ni = 0; ni < 4; ++ni) {
      const int o = (wx + ni * 16 + lm) * 32 + fs;
      bh[ni] = *(const bf16x8*)&sBh[o];
      bl[ni] = *(const bf16x8*)&sBl[o];
    }
    #pragma unroll
    for (int mi = 0; mi < 4; ++mi)
      #pragma unroll
      for (int ni = 0; ni < 4; ++ni) {
        acc[mi][ni] = __builtin_amdgcn_mfma_f32_16x16x32_bf16(ah[mi], bh[ni], acc[mi][ni], 0, 0, 0);
        acc[mi][ni] = __builtin_amdgcn_mfma_f32_16x16x32_bf16(ah[mi], bl[ni], acc[mi][ni], 0, 0, 0);
        acc[mi][ni] = __builtin_amdgcn_mfma_f32_16x16x32_bf16(al[mi], bh[ni], acc[mi][ni], 0, 0, 0);
      }
    __syncthreads();   // reads done: next step may overwrite
  }

  // epilogue: D[row=lq*4+r][col=lm] per 16x16 tile
  #pragma unroll
  for (int ni = 0; ni < 4; ++ni) {
    int col = n0 + wx + ni * 16 + lm;
    float bb = bias[col];
    #pragma unroll
    for (int mi = 0; mi < 4; ++mi) {
      int rbase = m0 + wy + mi * 16 + lq * 4;
      #pragma unroll
      for (int r = 0; r < 4; ++r)
        C[(size_t)(rbase + r) * Nn + col] = acc[mi][ni][r] + bb;
    }
  }
}

// ---------------------------------------------------------------------------
// GRU pointwise: h = (1-z)*n + z*h
__global__ void k_gru_pw(const float* __restrict__ gx, const float* __restrict__ gh,
                         float* __restrict__ h) {
  int i = blockIdx.x * 256 + threadIdx.x;        // 65536
  int b = i >> 9, j = i & 511;
  const float* gxb = gx + (size_t)b * G3n;
  const float* ghb = gh + (size_t)b * G3n;
  float rg = 1.f / (1.f + expf(-(gxb[j] + ghb[j])));
  float zg = 1.f / (1.f + expf(-(gxb[512 + j] + ghb[512 + j])));
  float ng = tanhf(gxb[1024 + j] + rg * ghb[1024 + j]);
  h[i] = (1.f - zg) * ng + zg * h[i];
}

// ---------------------------------------------------------------------------
// score[b,l] = sum_a tanh(q[b,a] + dproj[b*L+l, a]) * ws[a] + bs ; apply mask
__launch_bounds__(256)
__global__ void k_score(const float* __restrict__ dproj, const float* __restrict__ q,
                        const float* __restrict__ wsv, const float* __restrict__ bsv,
                        const int* __restrict__ mask, float* __restrict__ scoresf,
                        float* __restrict__ outScores, int t) {
  int w = blockIdx.x * 4 + (threadIdx.x >> 6);   // 0..25599
  int lane = threadIdx.x & 63;
  int b = w / Ln, l = w % Ln;
  const float4* dp4 = (const float4*)(dproj + (size_t)w * Nn);
  const float4* q4  = (const float4*)(q + (size_t)b * Nn);
  const float4* ws4 = (const float4*)wsv;

  float sum = 0.f;
  #pragma unroll
  for (int i = 0; i < 2; ++i) {
    int idx = lane + i * 64;                     // 128 float4 per row
    float4 d = dp4[idx], qq = q4[idx], wv = ws4[idx];
    sum += tanhf(qq.x + d.x) * wv.x + tanhf(qq.y + d.y) * wv.y
         + tanhf(qq.z + d.z) * wv.z + tanhf(qq.w + d.w) * wv.w;
  }
  #pragma unroll
  for (int off = 32; off > 0; off >>= 1) sum += __shfl_xor(sum, off, 64);

  if (lane == 0) {
    float v = sum + bsv[0];
    if (mask[w]) v = -1000000.0f;
    scoresf[w] = v;
    outScores[(size_t)b * (Tn * Ln) + t * Ln + l] = v;
  }
}

// ---------------------------------------------------------------------------
// per-batch argmax (first-index tie-break), update mask, gather selected row
__launch_bounds__(256)
__global__ void k_argmax(const float* __restrict__ scoresf, const float* __restrict__ sent,
                         float* __restrict__ s_row, int* __restrict__ mask,
                         float* __restrict__ outSel, int t) {
  int b = blockIdx.x;
  __shared__ int s_idx;
  int tid = threadIdx.x;
  if (tid < 64) {
    const float* sc = scoresf + (size_t)b * Ln;
    float best = -3.0e38f; int bi = 0;
    for (int l = tid; l < Ln; l += 64) {
      float v = sc[l];
      if (v > best) { best = v; bi = l; }        // increasing l: strict > keeps first
    }
    #pragma unroll
    for (int off = 32; off > 0; off >>= 1) {
      float ov = __shfl_down(best, off, 64);
      int   oi = __shfl_down(bi,   off, 64);
      if (ov > best || (ov == best && oi < bi)) { best = ov; bi = oi; }
    }
    if (tid == 0) s_idx = bi;
  }
  __syncthreads();
  int idx = s_idx;
  const float* src = sent + ((size_t)b * Ln + idx) * D2n;
  float* dstp = s_row + (size_t)b * D2n;
  int k = tid * 4;                               // 256 threads x 4 = 1024
  *(float4*)(dstp + k) = *(const float4*)(src + k);
  if (tid == 0) {
    mask[b * Ln + idx] = 1;
    outSel[(size_t)b * Tn + t] = (float)idx;
  }
}

// ---------------------------------------------------------------------------
extern "C" void kernel_launch(void* const* d_in, const int* in_sizes, int n_in,
                              void* d_out, int out_size, void* d_ws, size_t ws_size,
                              hipStream_t stream) {
  const float* sent = (const float*)d_in[0];
  const float* h0_w = (const float*)d_in[1];
  const float* h0_b = (const float*)d_in[2];
  const float* w_ih = (const float*)d_in[3];
  const float* w_hh = (const float*)d_in[4];
  const float* b_ih = (const float*)d_in[5];
  const float* b_hh = (const float*)d_in[6];
  const float* wq   = (const float*)d_in[7];
  const float* bq   = (const float*)d_in[8];
  const float* wd   = (const float*)d_in[9];
  const float* bd   = (const float*)d_in[10];
  const float* wsv  = (const float*)d_in[11];
  const float* bsv  = (const float*)d_in[12];

  float* wsf     = (float*)d_ws;
  float* d_proj  = wsf;                       // 25600*512 = 13107200
  float* s_row   = d_proj + 13107200;         // 128*1024
  float* h       = s_row + 131072;            // 128*512
  float* gx      = h + 65536;                 // 128*1536
  float* gh      = gx + 196608;               // 128*1536
  float* lastb   = gh + 196608;               // 128*512
  float* q       = lastb + 65536;             // 128*512
  float* scoresf = q + 65536;                 // 128*200
  int*   mask    = (int*)(scoresf + 25600);   // 128*200 ints
  ushort* Whi    = (ushort*)(mask + 25600);   // 512*1024 shorts
  ushort* Wlo    = Whi + 524288;              // 512*1024 shorts
  ushort* Ahi    = Wlo + 524288;              // 25600*1024 shorts
  ushort* Alo    = Ahi + 26214400;            // 25600*1024 shorts

  float* outScores = (float*)d_out;                       // (B, T, L) fp32
  float* outSel    = outScores + (size_t)Bn * Tn * Ln;    // (B, T) fp32

  hipMemsetAsync(s_row, 0, 131072 * sizeof(float), stream);       // s_prev(t=0) = 0
  hipMemsetAsync(mask, 0, 25600 * sizeof(int), stream);

  k_gather_lastb<<<256, 256, 0, stream>>>(sent, lastb);
  k_small_gemm<512, 1><<<dim3(8, 8), 256, 0, stream>>>(lastb, h0_w, h0_b, h, 512);
  k_split<<<512, 256, 0, stream>>>(wd, Whi, Wlo);         // 512*1024/4 float4
  k_split<<<25600, 256, 0, stream>>>(sent, Ahi, Alo);     // 25600*1024/4 float4
  k_dproj_mfma<<<800, 256, 0, stream>>>(Ahi, Alo, Whi, Wlo, bd, d_proj);

  for (int t = 0; t < Tn; ++t) {
    k_small_gemm<1024, 0><<<dim3(24, 8), 256, 0, stream>>>(s_row, w_ih, b_ih, gx, G3n);
    k_small_gemm<512, 0><<<dim3(24, 8), 256, 0, stream>>>(h, w_hh, b_hh, gh, G3n);
    k_gru_pw<<<256, 256, 0, stream>>>(gx, gh, h);
    k_small_gemm<512, 0><<<dim3(8, 8), 256, 0, stream>>>(h, wq, bq, q, 512);
    k_score<<<6400, 256, 0, stream>>>(d_proj, q, wsv, bsv, mask, scoresf, outScores, t);
    k_argmax<<<128, 256, 0, stream>>>(scoresf, sent, s_row, mask, outSel, t);
  }
}